// Round 1
// baseline (143.455 us; speedup 1.0000x reference)
//
#include <hip/hip_runtime.h>

// YOLO loss on MI355X. Inputs: yhat (N,52,52,255) f32, y (N,52,52,255) f32,
// anchors (3,3,2) f32, epoch (int, ignored: epoch=1 >= EPOCH_PRIOR=0 -> prior=0).
// Outputs: concat [coord(N), class(N), noobj(N), obj(N), prior(1)] f32.

constexpr int SD      = 52;
constexpr int S2CELLS = SD * SD;      // 2704
constexpr int CH      = 255;          // (5+80)*3
constexpr int ROWP    = 264;          // padded LDS row stride (floats); 264%32==8
constexpr int CPB     = 16;           // cells per block (4 waves x 4 groups)
constexpr int BPI     = S2CELLS / CPB; // 169 blocks per image (exact)
constexpr float EPSF  = 1e-6f;

__global__ __launch_bounds__(256) void yolo_loss_kernel(
    const float* __restrict__ yhat, const float* __restrict__ yt,
    const float* __restrict__ anchors, float* __restrict__ out, int N)
{
    __shared__ float shA[CPB][ROWP];
    __shared__ float shT[CPB][ROWP];
    __shared__ float red[4][4];

    const int tid  = threadIdx.x;
    const int wv   = tid >> 6;
    const int lane = tid & 63;
    const int grp  = lane >> 4;
    const int sub  = lane & 15;
    const int cellLocal = wv * 4 + grp;

    const int n          = blockIdx.x / BPI;
    const int cellInImg0 = (blockIdx.x % BPI) * CPB;

    // anchors[scale_idx=2][b][wh] -> flat offset 12 + 2b
    const float aw0 = anchors[12], ah0 = anchors[13];
    const float aw1 = anchors[14], ah1 = anchors[15];
    const float aw2 = anchors[16], ah2 = anchors[17];

    // ---- stage 16 contiguous rows of both tensors into LDS (coalesced) ----
    const size_t gbase = ((size_t)blockIdx.x) * (size_t)(CPB * CH);
    for (int e = tid; e < CPB * CH; e += 256) {
        int c   = e / CH;          // compiler magic-mul
        int off = e - c * CH;
        shA[c][off] = yhat[gbase + e];
        shT[c][off] = yt[gbase + e];
    }
    __syncthreads();

    // ---- per-group (16 lanes) cell computation ----
    const int cellImg = cellInImg0 + cellLocal;
    const float jf   = (float)(cellImg % SD);
    const float if_  = (float)(cellImg / SD);
    const float invS = 1.0f / (float)SD;
    const float* A = shA[cellLocal];
    const float* T = shT[cellLocal];

    float hx1[3], hx2[3], hy1[3], hy2[3], ha[3], hcf[3];
    float tx1[3], tx2[3], ty1[3], ty2[3], ta[3], tcf[3];
#pragma unroll
    for (int b = 0; b < 3; b++) {
        {
            float x = A[b*85+0], yy = A[b*85+1], w = A[b*85+2], h = A[b*85+3];
            float cx = (x + jf) * invS, cy = (yy + if_) * invS;
            hx1[b] = cx - 0.5f*w; hx2[b] = cx + 0.5f*w;
            hy1[b] = cy - 0.5f*h; hy2[b] = cy + 0.5f*h;
            ha[b]  = (hx2[b]-hx1[b]) * (hy2[b]-hy1[b]);
            hcf[b] = A[b*85+4];
        }
        {
            float x = T[b*85+0], yy = T[b*85+1], w = T[b*85+2], h = T[b*85+3];
            float cx = (x + jf) * invS, cy = (yy + if_) * invS;
            tx1[b] = cx - 0.5f*w; tx2[b] = cx + 0.5f*w;
            ty1[b] = cy - 0.5f*h; ty2[b] = cy + 0.5f*h;
            ta[b]  = (tx2[b]-tx1[b]) * (ty2[b]-ty1[b]);
            tcf[b] = T[b*85+4];
        }
    }

    float iou[3][3];
#pragma unroll
    for (int bp = 0; bp < 3; bp++) {
#pragma unroll
        for (int bt = 0; bt < 3; bt++) {
            float wi = fminf(hx2[bp], tx2[bt]) - fmaxf(hx1[bp], tx1[bt]);
            wi = fmaxf(wi, 0.0f);
            float hi = fminf(hy2[bp], ty2[bt]) - fmaxf(hy1[bp], ty1[bt]);
            hi = fmaxf(hi, 0.0f);
            float inter = wi * hi;
            float uni   = ha[bp] + ta[bt] - inter;
            iou[bp][bt] = inter / (uni + EPSF);
        }
    }

    // no-obj: per pred box, max IoU over targets
    float noobj_c = 0.0f;
#pragma unroll
    for (int bp = 0; bp < 3; bp++) {
        float m = fmaxf(fmaxf(iou[bp][0], iou[bp][1]), iou[bp][2]);
        noobj_c += (m < 0.7f) ? hcf[bp]*hcf[bp] : 0.0f;
    }

    // argmax over pred boxes per target box (first-max ties, like jnp.argmax)
    int sel[3];
#pragma unroll
    for (int bt = 0; bt < 3; bt++) {
        int s = 0; float v = iou[0][bt];
        if (iou[1][bt] > v) { v = iou[1][bt]; s = 1; }
        if (iou[2][bt] > v) { s = 2; }
        sel[bt] = s;
    }

    float coord_c = 0.0f, obj_c = 0.0f;
    float ho[3];
#pragma unroll
    for (int bt = 0; bt < 3; bt++) {
        int sp = sel[bt];
        const float* ph = &A[sp * 85];
        const float* pt = &T[bt * 85];
        float hoo = (pt[4] > 0.0f) ? 1.0f : 0.0f;
        ho[bt] = hoo;
        float awp = (sp == 0) ? aw0 : ((sp == 1) ? aw1 : aw2);
        float ahp = (sp == 0) ? ah0 : ((sp == 1) ? ah1 : ah2);
        float awt = (bt == 0) ? aw0 : ((bt == 1) ? aw1 : aw2);
        float aht = (bt == 0) ? ah0 : ((bt == 1) ? ah1 : ah2);
        float dx = ph[0] - pt[0];
        float dy = ph[1] - pt[1];
        float dlw = logf(ph[2] / awp + EPSF) - logf(pt[2] / awt + EPSF);
        float dlh = logf(ph[3] / ahp + EPSF) - logf(pt[3] / aht + EPSF);
        float csum = dx*dx + dy*dy + dlw*dlw + dlh*dlh;
        coord_c += csum * hoo * (2.0f - pt[2] * pt[3]);
        float dcf = ph[4] - pt[4];
        obj_c += dcf * dcf * hoo;
    }

    // class loss: 80 classes x 3 target boxes distributed over 16 lanes
    float class_c = 0.0f;
#pragma unroll
    for (int b = 0; b < 3; b++) {
        int sp = sel[b];
        const float* pa = &A[sp * 85 + 5];
        const float* pt = &T[b  * 85 + 5];
        float s = 0.0f;
#pragma unroll
        for (int k = 0; k < 5; k++) {
            int c = sub + k * 16;   // covers 0..79 exactly
            float d = pa[c] - pt[c];
            s += d * d;
        }
        class_c += s * ho[b];
    }

    // ---- reductions ----
    // class: butterfly within 16-lane group
    class_c += __shfl_xor(class_c, 1, 64);
    class_c += __shfl_xor(class_c, 2, 64);
    class_c += __shfl_xor(class_c, 4, 64);
    class_c += __shfl_xor(class_c, 8, 64);
    // keep one lane per group, then fold groups (lanes 0,16,32,48)
    if (sub != 0) { coord_c = 0.f; class_c = 0.f; noobj_c = 0.f; obj_c = 0.f; }
    coord_c += __shfl_xor(coord_c, 16, 64); coord_c += __shfl_xor(coord_c, 32, 64);
    class_c += __shfl_xor(class_c, 16, 64); class_c += __shfl_xor(class_c, 32, 64);
    noobj_c += __shfl_xor(noobj_c, 16, 64); noobj_c += __shfl_xor(noobj_c, 32, 64);
    obj_c   += __shfl_xor(obj_c,   16, 64); obj_c   += __shfl_xor(obj_c,   32, 64);

    if (lane == 0) {
        red[wv][0] = coord_c; red[wv][1] = class_c;
        red[wv][2] = noobj_c; red[wv][3] = obj_c;
    }
    __syncthreads();
    if (tid < 4) {
        float s = red[0][tid] + red[1][tid] + red[2][tid] + red[3][tid];
        atomicAdd(&out[tid * N + n], s);
    }
}

extern "C" void kernel_launch(void* const* d_in, const int* in_sizes, int n_in,
                              void* d_out, int out_size, void* d_ws, size_t ws_size,
                              hipStream_t stream) {
    const float* yhat = (const float*)d_in[0];
    const float* yv   = (const float*)d_in[1];
    const float* anc  = (const float*)d_in[2];
    float* out = (float*)d_out;

    const int N = in_sizes[0] / (S2CELLS * CH);

    // zero outputs (also writes prior_loss = 0 at [4N])
    hipMemsetAsync(d_out, 0, (size_t)out_size * sizeof(float), stream);

    dim3 grid(N * BPI);
    yolo_loss_kernel<<<grid, 256, 0, stream>>>(yhat, yv, anc, out, N);
}

// Round 2
// 116.249 us; speedup vs baseline: 1.2340x; 1.2340x over previous
//
#include <hip/hip_runtime.h>

// YOLO loss on MI355X. Inputs: yhat (N,52,52,255) f32, y (N,52,52,255) f32,
// anchors (3,3,2) f32, epoch (ignored: epoch=1 >= EPOCH_PRIOR=0 -> prior=0).
// Outputs: concat [coord(N), class(N), noobj(N), obj(N), prior(1)] f32.
//
// Design: no LDS staging (data is read ~once; box reads are group-uniform
// broadcasts, class reads are 16-lane contiguous 64B runs -> L1/L2 handle it).
// One cell per 16-lane group, 16 cells per 256-thread block. Fast log/rcp
// intrinsics instead of libm logf / precise fdiv (the R0 VALU hog).

constexpr int SD      = 52;
constexpr int S2CELLS = SD * SD;        // 2704
constexpr int CH      = 255;            // (5+80)*3
constexpr int CPB     = 16;             // cells per block (4 waves x 4 groups)
constexpr float EPSF  = 1e-6f;

__device__ __forceinline__ float flog(float x) {
    // natural log via v_log_f32 (log2) * ln(2)
    return __builtin_amdgcn_logf(x) * 0.69314718055994531f;
}
__device__ __forceinline__ float frcp(float x) {
    return __builtin_amdgcn_rcpf(x);
}

__global__ __launch_bounds__(256) void yolo_loss_kernel(
    const float* __restrict__ yhat, const float* __restrict__ yt,
    const float* __restrict__ anchors, float* __restrict__ out, int N)
{
    __shared__ float red[4][4];

    const int tid  = threadIdx.x;
    const int wv   = tid >> 6;
    const int lane = tid & 63;
    const int grp  = lane >> 4;
    const int sub  = lane & 15;

    // global cell index; each 16-lane group owns one cell
    const int cellGlobal = blockIdx.x * CPB + wv * 4 + grp;
    const int n       = cellGlobal / S2CELLS;          // magic-mul
    const int cellImg = cellGlobal - n * S2CELLS;
    const int irow    = cellImg / SD;                  // magic-mul
    const int jcol    = cellImg - irow * SD;
    const float jf   = (float)jcol;
    const float if_  = (float)irow;
    const float invS = 1.0f / (float)SD;

    const float* __restrict__ A = yhat + (size_t)cellGlobal * CH;
    const float* __restrict__ T = yt   + (size_t)cellGlobal * CH;

    // anchors[scale_idx=2][b][wh] -> flat offset 12 + 2b; precompute recips
    const float aw0 = anchors[12], ah0 = anchors[13];
    const float aw1 = anchors[14], ah1 = anchors[15];
    const float aw2 = anchors[16], ah2 = anchors[17];
    const float rw0 = frcp(aw0), rh0 = frcp(ah0);
    const float rw1 = frcp(aw1), rh1 = frcp(ah1);
    const float rw2 = frcp(aw2), rh2 = frcp(ah2);

    // ---- box phase (group-uniform loads: 16 lanes same address) ----
    float hx1[3], hx2[3], hy1[3], hy2[3], ha[3], hcf[3], hw[3], hh[3];
    float tx1[3], tx2[3], ty1[3], ty2[3], ta[3], tcf[3], tw[3], th[3];
    float hxr[3], hyr[3], txr[3], tyr[3];
#pragma unroll
    for (int b = 0; b < 3; b++) {
        const float* p = &A[b * 85];
        float x = p[0], yy = p[1], w = p[2], h = p[3];
        hxr[b] = x; hyr[b] = yy; hw[b] = w; hh[b] = h; hcf[b] = p[4];
        float cx = (x + jf) * invS, cy = (yy + if_) * invS;
        hx1[b] = cx - 0.5f * w; hx2[b] = cx + 0.5f * w;
        hy1[b] = cy - 0.5f * h; hy2[b] = cy + 0.5f * h;
        ha[b]  = (hx2[b] - hx1[b]) * (hy2[b] - hy1[b]);
    }
#pragma unroll
    for (int b = 0; b < 3; b++) {
        const float* p = &T[b * 85];
        float x = p[0], yy = p[1], w = p[2], h = p[3];
        txr[b] = x; tyr[b] = yy; tw[b] = w; th[b] = h; tcf[b] = p[4];
        float cx = (x + jf) * invS, cy = (yy + if_) * invS;
        tx1[b] = cx - 0.5f * w; tx2[b] = cx + 0.5f * w;
        ty1[b] = cy - 0.5f * h; ty2[b] = cy + 0.5f * h;
        ta[b]  = (tx2[b] - tx1[b]) * (ty2[b] - ty1[b]);
    }

    float iou[3][3];
#pragma unroll
    for (int bp = 0; bp < 3; bp++) {
#pragma unroll
        for (int bt = 0; bt < 3; bt++) {
            float wi = fminf(hx2[bp], tx2[bt]) - fmaxf(hx1[bp], tx1[bt]);
            wi = fmaxf(wi, 0.0f);
            float hi = fminf(hy2[bp], ty2[bt]) - fmaxf(hy1[bp], ty1[bt]);
            hi = fmaxf(hi, 0.0f);
            float inter = wi * hi;
            float uni   = ha[bp] + ta[bt] - inter;
            iou[bp][bt] = inter * frcp(uni + EPSF);
        }
    }

    // no-obj: per pred box, max IoU over targets (target = 0, NO_OBJ_V3)
    float noobj_c = 0.0f;
#pragma unroll
    for (int bp = 0; bp < 3; bp++) {
        float m = fmaxf(fmaxf(iou[bp][0], iou[bp][1]), iou[bp][2]);
        noobj_c += (m < 0.7f) ? hcf[bp] * hcf[bp] : 0.0f;
    }

    // argmax over pred boxes per target box (first-max ties, like jnp.argmax)
    int sel[3];
#pragma unroll
    for (int bt = 0; bt < 3; bt++) {
        int s = 0; float v = iou[0][bt];
        if (iou[1][bt] > v) { v = iou[1][bt]; s = 1; }
        if (iou[2][bt] > v) { s = 2; }
        sel[bt] = s;
    }

    float coord_c = 0.0f, obj_c = 0.0f;
    float ho[3];
#pragma unroll
    for (int bt = 0; bt < 3; bt++) {
        int sp = sel[bt];
        float hoo = (tcf[bt] > 0.0f) ? 1.0f : 0.0f;
        ho[bt] = hoo;
        // gathered pred values (statically indexed via ternaries)
        float phx = (sp == 0) ? hxr[0] : ((sp == 1) ? hxr[1] : hxr[2]);
        float phy = (sp == 0) ? hyr[0] : ((sp == 1) ? hyr[1] : hyr[2]);
        float phw = (sp == 0) ? hw[0]  : ((sp == 1) ? hw[1]  : hw[2]);
        float phh = (sp == 0) ? hh[0]  : ((sp == 1) ? hh[1]  : hh[2]);
        float phc = (sp == 0) ? hcf[0] : ((sp == 1) ? hcf[1] : hcf[2]);
        float rwp = (sp == 0) ? rw0 : ((sp == 1) ? rw1 : rw2);
        float rhp = (sp == 0) ? rh0 : ((sp == 1) ? rh1 : rh2);
        float rwt = (bt == 0) ? rw0 : ((bt == 1) ? rw1 : rw2);
        float rht = (bt == 0) ? rh0 : ((bt == 1) ? rh1 : rh2);
        float dx = phx - txr[bt];
        float dy = phy - tyr[bt];
        float dlw = flog(phw * rwp + EPSF) - flog(tw[bt] * rwt + EPSF);
        float dlh = flog(phh * rhp + EPSF) - flog(th[bt] * rht + EPSF);
        float csum = dx * dx + dy * dy + dlw * dlw + dlh * dlh;
        coord_c += csum * hoo * (2.0f - tw[bt] * th[bt]);
        float dcf = phc - tcf[bt];
        obj_c += dcf * dcf * hoo;
    }

    // ---- class loss: 80 classes x 3 target boxes over 16 lanes ----
    // reads: 16-lane contiguous 64B runs from global (coalesced per group)
    float class_c = 0.0f;
#pragma unroll
    for (int b = 0; b < 3; b++) {
        int sp = sel[b];
        const float* pa = A + sp * 85 + 5;
        const float* pt = T + b  * 85 + 5;
        float s = 0.0f;
#pragma unroll
        for (int k = 0; k < 5; k++) {
            int c = sub + k * 16;   // covers 0..79 exactly
            float d = pa[c] - pt[c];
            s += d * d;
        }
        class_c += s * ho[b];
    }

    // ---- reductions ----
    class_c += __shfl_xor(class_c, 1, 64);
    class_c += __shfl_xor(class_c, 2, 64);
    class_c += __shfl_xor(class_c, 4, 64);
    class_c += __shfl_xor(class_c, 8, 64);
    if (sub != 0) { coord_c = 0.f; class_c = 0.f; noobj_c = 0.f; obj_c = 0.f; }
    coord_c += __shfl_xor(coord_c, 16, 64); coord_c += __shfl_xor(coord_c, 32, 64);
    class_c += __shfl_xor(class_c, 16, 64); class_c += __shfl_xor(class_c, 32, 64);
    noobj_c += __shfl_xor(noobj_c, 16, 64); noobj_c += __shfl_xor(noobj_c, 32, 64);
    obj_c   += __shfl_xor(obj_c,   16, 64); obj_c   += __shfl_xor(obj_c,   32, 64);

    if (lane == 0) {
        red[wv][0] = coord_c; red[wv][1] = class_c;
        red[wv][2] = noobj_c; red[wv][3] = obj_c;
    }
    __syncthreads();
    if (tid < 4) {
        float s = red[0][tid] + red[1][tid] + red[2][tid] + red[3][tid];
        atomicAdd(&out[tid * N + n], s);
    }
}

extern "C" void kernel_launch(void* const* d_in, const int* in_sizes, int n_in,
                              void* d_out, int out_size, void* d_ws, size_t ws_size,
                              hipStream_t stream) {
    const float* yhat = (const float*)d_in[0];
    const float* yv   = (const float*)d_in[1];
    const float* anc  = (const float*)d_in[2];
    float* out = (float*)d_out;

    const int N = in_sizes[0] / (S2CELLS * CH);

    // zero outputs (also writes prior_loss = 0 at [4N])
    hipMemsetAsync(d_out, 0, (size_t)out_size * sizeof(float), stream);

    dim3 grid((N * S2CELLS) / CPB);
    yolo_loss_kernel<<<grid, 256, 0, stream>>>(yhat, yv, anc, out, N);
}